// Round 19
// baseline (567.160 us; speedup 1.0000x reference)
//
#include <hip/hip_runtime.h>
#include <math.h>

#define NN 100000
#define NE 1600000
#define HID 128
#define INCH 256
#define OUTC 40
#define NLAYERS 8
#define NBUCK 391   // ceil(NN/256)
#define EPB 4096
#define CAP 6144
#define LW 136      // LDS row stride in ushorts (272 B)

typedef __attribute__((ext_vector_type(8))) short bf16x8;
typedef __attribute__((ext_vector_type(4))) float f32x4;
typedef __attribute__((ext_vector_type(2))) float f32x2;

static __device__ inline unsigned short f2bf(float f) {
  unsigned u = __float_as_uint(f);
  unsigned r = (u + 0x7fff + ((u >> 16) & 1)) >> 16;
  return (unsigned short)r;
}
static __device__ inline float bflo(unsigned u) { return __uint_as_float(u << 16); }
static __device__ inline float bfhi(unsigned u) { return __uint_as_float(u & 0xffff0000u); }
static __device__ inline unsigned char f2fp8(float f) {
  return (unsigned char)(__builtin_amdgcn_cvt_pk_fp8_f32(f, f, 0, false) & 0xff);
}

// ---------------- preprocessing (atomic-light counting sort + degree perm) ----------------

static __global__ void k_zerob(int* __restrict__ bcnt, int* __restrict__ dbin) {
  int i = blockIdx.x * 256 + threadIdx.x;
  if (i < NBUCK) bcnt[i] = 0;
  if (i < 64) dbin[i] = 0;
}

static __global__ __launch_bounds__(256) void k_bhist(const int* __restrict__ ei,
                                                      int* __restrict__ bcnt) {
  __shared__ int lh[NBUCK + 1];
  int t = threadIdx.x;
  for (int i = t; i <= NBUCK; i += 256) lh[i] = 0;
  __syncthreads();
  int e0 = blockIdx.x * EPB;
  for (int k = t; k < EPB; k += 256) {
    int e = e0 + k;
    if (e < NE) atomicAdd(&lh[ei[NE + e] >> 8], 1);
  }
  __syncthreads();
  for (int i = t; i < NBUCK; i += 256)
    if (lh[i]) atomicAdd(&bcnt[i], lh[i]);
}

static __global__ void k_bscan(const int* __restrict__ bcnt, int* __restrict__ boffs,
                               int* __restrict__ bcur, int* __restrict__ offs) {
  __shared__ int sd[512];
  int t = threadIdx.x;
  sd[t] = (t < NBUCK) ? bcnt[t] : 0;
  __syncthreads();
  for (int d = 1; d < 512; d <<= 1) {
    int v = (t >= d) ? sd[t - d] : 0;
    __syncthreads();
    sd[t] += v;
    __syncthreads();
  }
  if (t < NBUCK) {
    boffs[t + 1] = sd[t];
    bcur[t] = sd[t] - bcnt[t];
  }
  if (t == 0) { boffs[0] = 0; offs[NN] = NE; }
}

static __global__ __launch_bounds__(256) void k_sortA(const int* __restrict__ ei,
                                                      int* __restrict__ bcur,
                                                      int2* __restrict__ stage) {
  __shared__ int lsrc[EPB], ldst[EPB];
  __shared__ int lh[NBUCK + 1], lbase[NBUCK + 1], lcur[NBUCK + 1];
  int t = threadIdx.x;
  int e0 = blockIdx.x * EPB;
  for (int k = t; k < EPB; k += 256) {
    int e = e0 + k;
    lsrc[k] = (e < NE) ? ei[e] : -1;
    ldst[k] = (e < NE) ? ei[NE + e] : -1;
  }
  for (int i = t; i <= NBUCK; i += 256) lh[i] = 0;
  __syncthreads();
  for (int k = t; k < EPB; k += 256)
    if (ldst[k] >= 0) atomicAdd(&lh[ldst[k] >> 8], 1);
  __syncthreads();
  for (int i = t; i < NBUCK; i += 256) {
    int c = lh[i];
    lbase[i] = c ? atomicAdd(&bcur[i], c) : 0;
    lcur[i] = 0;
  }
  __syncthreads();
  for (int k = t; k < EPB; k += 256) {
    int d = ldst[k];
    if (d >= 0) {
      int bu = d >> 8;
      int r = atomicAdd(&lcur[bu], 1);
      stage[lbase[bu] + r] = make_int2(lsrc[k], d);
    }
  }
}

static __global__ __launch_bounds__(256) void k_degs(
    const int2* __restrict__ stage, const int* __restrict__ boffs,
    int* __restrict__ offs, float* __restrict__ dinv, int* __restrict__ cursor,
    int* __restrict__ deg, int* __restrict__ dbin) {
  __shared__ int lcnt[256];
  __shared__ int sd[256];
  __shared__ int lhd[64];
  int b = blockIdx.x, t = threadIdx.x;
  int sb = boffs[b], se = boffs[b + 1];
  int cntb = se - sb;
  int nb0 = b << 8;
  lcnt[t] = 0;
  if (t < 64) lhd[t] = 0;
  __syncthreads();
  for (int k = t; k < cntb; k += 256) atomicAdd(&lcnt[stage[sb + k].y - nb0], 1);
  __syncthreads();
  int v = lcnt[t];
  sd[t] = v;
  __syncthreads();
  for (int d = 1; d < 256; d <<= 1) {
    int u = (t >= d) ? sd[t - d] : 0;
    __syncthreads();
    sd[t] += u;
    __syncthreads();
  }
  int n = nb0 + t;
  if (n < NN) {
    int o = sb + sd[t] - v;
    offs[n] = o;
    cursor[n] = o;
    dinv[n] = rsqrtf((float)(v + 1));
    deg[n] = v;
    int bin = 63 - (v > 63 ? 63 : v);  // heavy nodes first
    atomicAdd(&lhd[bin], 1);
  }
  __syncthreads();
  if (t < 64 && lhd[t]) atomicAdd(&dbin[t], lhd[t]);
}

static __global__ void k_dscan(const int* __restrict__ dbin, int* __restrict__ dcur) {
  __shared__ int sd[64];
  int t = threadIdx.x;
  sd[t] = dbin[t];
  __syncthreads();
  if (t == 0) {
    int a = 0;
    for (int i = 0; i < 64; ++i) { int v = sd[i]; sd[i] = a; a += v; }
  }
  __syncthreads();
  dcur[t] = sd[t];
}

static __global__ __launch_bounds__(256) void k_perm(const int* __restrict__ deg,
                                                     int* __restrict__ dcur,
                                                     int* __restrict__ perm,
                                                     int* __restrict__ inv) {
  __shared__ int lh[64], lbase[64], lcur[64];
  int t = threadIdx.x;
  int n = blockIdx.x * 256 + t;
  if (t < 64) { lh[t] = 0; lcur[t] = 0; }
  __syncthreads();
  int bin = 0;
  if (n < NN) {
    int d = deg[n];
    bin = 63 - (d > 63 ? 63 : d);
    atomicAdd(&lh[bin], 1);
  }
  __syncthreads();
  if (t < 64) lbase[t] = lh[t] ? atomicAdd(&dcur[t], lh[t]) : 0;
  __syncthreads();
  if (n < NN) {
    int r = atomicAdd(&lcur[bin], 1);
    int pos = lbase[bin] + r;
    perm[pos] = n;
    inv[n] = pos;
  }
}

// node header for fused: {offs_begin, offs_end, dinv^2, 0} in permuted order
static __global__ void k_hdr(const int* __restrict__ perm, const int* __restrict__ offs,
                             const float* __restrict__ dinv, int4* __restrict__ hdr) {
  int i = blockIdx.x * 256 + threadIdx.x;
  if (i < NN) {
    int n = perm[i];
    float d = dinv[n];
    hdr[i] = make_int4(offs[n], offs[n + 1], __float_as_int(d * d), 0);
  }
}

// edata.x = inv[src] (permuted-space source index)
static __global__ __launch_bounds__(256) void k_passB2(
    const int2* __restrict__ stage, const int* __restrict__ boffs,
    const int* __restrict__ offs, const float* __restrict__ dinv,
    const int* __restrict__ inv, int* __restrict__ cursor, int2* __restrict__ edata) {
  __shared__ int2 lbuf[CAP];
  __shared__ int lcur[256];
  int b = blockIdx.x, t = threadIdx.x;
  int sb = boffs[b], se = boffs[b + 1];
  int cntb = se - sb;
  int nb0 = b << 8;
  if (cntb <= CAP) {
    if (nb0 + t < NN) lcur[t] = offs[nb0 + t] - sb;
    __syncthreads();
    for (int k = t; k < cntb; k += 256) {
      int2 sd_ = stage[sb + k];
      float w = dinv[sd_.x] * dinv[sd_.y];
      int p = atomicAdd(&lcur[sd_.y - nb0], 1);
      lbuf[p] = make_int2(inv[sd_.x], __float_as_int(w));
    }
    __syncthreads();
    for (int k = t; k < cntb; k += 256) edata[sb + k] = lbuf[k];
  } else {
    for (int k = t; k < cntb; k += 256) {
      int2 sd_ = stage[sb + k];
      float w = dinv[sd_.x] * dinv[sd_.y];
      int p = atomicAdd(&cursor[sd_.y], 1);
      edata[p] = make_int2(inv[sd_.x], __float_as_int(w));
    }
  }
}

// ---------------- merged weight conversion ----------------
static __global__ void k_cvtall(const float* __restrict__ W1, const float* __restrict__ CW,
                                const float* __restrict__ W2, unsigned short* __restrict__ wt1,
                                unsigned short* __restrict__ wtl,
                                unsigned short* __restrict__ wt2) {
  int idx = blockIdx.x * 256 + threadIdx.x;
  if (idx < INCH * HID) {
    int k = idx >> 7, n = idx & 127;
    wt1[(size_t)n * INCH + k] = f2bf(W1[idx]);
  } else if (idx < INCH * HID + NLAYERS * HID * HID) {
    int r = idx - INCH * HID;
    int l = r >> 14, rem = r & 16383;
    int k = rem >> 7, n = rem & 127;
    float beta = logf(1.0f / (float)(l + 1) + 1.0f);
    float v = beta * CW[r];
    if (k == n) v += 1.0f - beta;
    wtl[(size_t)l * HID * HID + n * HID + k] = f2bf(v);
  } else if (idx < INCH * HID + NLAYERS * HID * HID + 48 * HID) {
    int r = idx - INCH * HID - NLAYERS * HID * HID;
    int n = r >> 7, k = r & 127;
    wt2[r] = (n < OUTC) ? f2bf(W2[(size_t)k * OUTC + n]) : 0;
  }
}

// ---------------- lin1: 32-row tiles, streaming reads, scattered row writes ----------
__global__ __launch_bounds__(256, 4) void k_lin1(
    const float* __restrict__ A32, const unsigned short* __restrict__ Wt16,
    const float* __restrict__ bias, const int* __restrict__ inv,
    unsigned short* __restrict__ C16, unsigned char* __restrict__ C8, int M) {
  __shared__ unsigned short lds[32 * LW];
  __shared__ int ldst[32];
  const int tid = threadIdx.x;
  const int lane = tid & 63;
  const int wid = tid >> 6;
  const int j = lane & 15, g = lane >> 4;
  const int rq = (wid >> 1) * 16;
  const int colbase = (wid & 1) * 64;
  const int m0 = blockIdx.x * 32;

  if (tid < 32) {
    int r = m0 + tid;
    ldst[tid] = inv[r >= M ? M - 1 : r];
  }

  f32x4 acc[4];
  const f32x4 zero = {0.f, 0.f, 0.f, 0.f};
#pragma unroll
  for (int c = 0; c < 4; ++c) acc[c] = zero;

#pragma unroll 1
  for (int kc = 0; kc < 2; ++kc) {
    __syncthreads();
#pragma unroll
    for (int u = 0; u < 2; ++u) {
      int idx = u * 256 + tid;  // 0..511
      int row = idx >> 4, ch = idx & 15;
      int grow = m0 + row;
      if (grow >= M) grow = M - 1;
      const float* p = A32 + (size_t)grow * INCH + kc * 128 + ch * 8;
      float4 u0 = *(const float4*)p;
      float4 u1 = *(const float4*)(p + 4);
      bf16x8 v;
      v[0] = (short)f2bf(u0.x); v[1] = (short)f2bf(u0.y);
      v[2] = (short)f2bf(u0.z); v[3] = (short)f2bf(u0.w);
      v[4] = (short)f2bf(u1.x); v[5] = (short)f2bf(u1.y);
      v[6] = (short)f2bf(u1.z); v[7] = (short)f2bf(u1.w);
      *(bf16x8*)&lds[row * LW + ch * 8] = v;
    }
    __syncthreads();
    bf16x8 bfrag[4][4];
#pragma unroll
    for (int c = 0; c < 4; ++c)
#pragma unroll
      for (int s = 0; s < 4; ++s)
        bfrag[c][s] = *(const bf16x8*)(Wt16 + (size_t)(colbase + 16 * c + j) * INCH +
                                       kc * 128 + 32 * s + 8 * g);
    bf16x8 af[4];
#pragma unroll
    for (int s = 0; s < 4; ++s)
      af[s] = *(const bf16x8*)&lds[(rq + j) * LW + 32 * s + 8 * g];
#pragma unroll
    for (int s = 0; s < 4; ++s)
#pragma unroll
      for (int c = 0; c < 4; ++c)
        acc[c] = __builtin_amdgcn_mfma_f32_16x16x32_bf16(af[s], bfrag[c][s], acc[c], 0, 0, 0);
  }

  // stage result tile (bf16) into LDS
  __syncthreads();
#pragma unroll
  for (int i = 0; i < 4; ++i) {
    const int row = rq + 4 * g + i;
#pragma unroll
    for (int c = 0; c < 4; ++c) {
      const int col = colbase + 16 * c + j;
      lds[row * LW + col] = f2bf(fmaxf(acc[c][i] + bias[col], 0.f));
    }
  }
  __syncthreads();

  // scattered writes: thread -> (row = tid>>3, 16-short chunk = tid&7)
  {
    const int r = tid >> 3, q = tid & 7;
    if (m0 + r < M) {
      const unsigned short* src = &lds[r * LW + q * 16];
      uint4 v0 = *(const uint4*)(src);
      uint4 v1 = *(const uint4*)(src + 8);
      size_t base = (size_t)ldst[r] * HID + q * 16;
      *(uint4*)(C16 + base) = v0;
      *(uint4*)(C16 + base + 8) = v1;
      unsigned char q8[16];
      const unsigned* uu0 = (const unsigned*)&v0;
      const unsigned* uu1 = (const unsigned*)&v1;
#pragma unroll
      for (int s = 0; s < 4; ++s) {
        q8[2 * s] = f2fp8(bflo(uu0[s]));      q8[2 * s + 1] = f2fp8(bfhi(uu0[s]));
        q8[8 + 2 * s] = f2fp8(bflo(uu1[s]));  q8[9 + 2 * s] = f2fp8(bfhi(uu1[s]));
      }
      *(uint4*)(C8 + base) = *(const uint4*)&q8[0];
    }
  }
}

// ---------------- fused layer: agg (fp8 gather, 2-deep pipeline) + GEMM ----------------
#define ACCD(U, O, W)                                                   \
  {                                                                     \
    f32x2 lo_ = __builtin_amdgcn_cvt_pk_f32_fp8((U), false);            \
    f32x2 hi_ = __builtin_amdgcn_cvt_pk_f32_fp8((U), true);             \
    acc[(O) + 0] = fmaf((W), lo_.x, acc[(O) + 0]);                      \
    acc[(O) + 1] = fmaf((W), lo_.y, acc[(O) + 1]);                      \
    acc[(O) + 2] = fmaf((W), hi_.x, acc[(O) + 2]);                      \
    acc[(O) + 3] = fmaf((W), hi_.y, acc[(O) + 3]);                      \
  }

#define ACCROW8(VA, VB, W)                                              \
  ACCD((VA).x, 0, W) ACCD((VA).y, 4, W) ACCD((VA).z, 8, W) ACCD((VA).w, 12, W) \
  ACCD((VB).x, 16, W) ACCD((VB).y, 20, W) ACCD((VB).z, 24, W) ACCD((VB).w, 28, W)

__global__ __launch_bounds__(256) void k_fused(
    const unsigned char* __restrict__ h8, const unsigned short* __restrict__ x016,
    const int4* __restrict__ hdr, const int2* __restrict__ edata,
    const unsigned short* __restrict__ Wt16, unsigned char* __restrict__ h8out,
    unsigned short* __restrict__ C16, int M) {
  __shared__ unsigned short lds[64 * LW];
  const int tid = threadIdx.x;
  const int m0 = blockIdx.x * 64;
  const int newid = m0 + (tid >> 2);
  const int cq = (tid & 3) * 32;

  float acc[32];
#pragma unroll
  for (int q = 0; q < 32; ++q) acc[q] = 0.f;

  unsigned short q16[32];
  if (newid < M) {
    const int4 hd = hdr[newid];
    const int b = hd.x, e = hd.y;
    {  // self loop
      const unsigned char* p = h8 + (size_t)newid * HID + cq;
      uint4 s0 = *(const uint4*)p, s1 = *(const uint4*)(p + 16);
      float w = __int_as_float(hd.z);
      ACCROW8(s0, s1, w)
    }
    int i = b;
    int2 n0, n1;
    if (i + 3 < e) { n0 = edata[i]; n1 = edata[i + 1]; }
    for (; i + 3 < e; i += 2) {
      int2 c0 = n0, c1 = n1;
      n0 = edata[i + 2];
      n1 = edata[i + 3];
      const unsigned char* p0 = h8 + (size_t)c0.x * HID + cq;
      const unsigned char* p1 = h8 + (size_t)c1.x * HID + cq;
      uint4 r0 = *(const uint4*)p0, r1 = *(const uint4*)(p0 + 16);
      uint4 r2 = *(const uint4*)p1, r3 = *(const uint4*)(p1 + 16);
      float w0 = __int_as_float(c0.y), w1 = __int_as_float(c1.y);
      ACCROW8(r0, r1, w0)
      ACCROW8(r2, r3, w1)
    }
    for (; i < e; ++i) {
      int2 e0 = edata[i];
      const unsigned char* p0 = h8 + (size_t)e0.x * HID + cq;
      uint4 r0 = *(const uint4*)p0, r1 = *(const uint4*)(p0 + 16);
      float w0 = __int_as_float(e0.y);
      ACCROW8(r0, r1, w0)
    }
    const unsigned short* px = x016 + (size_t)newid * HID + cq;
    uint4 xa = *(const uint4*)px, xb = *(const uint4*)(px + 8);
    uint4 xc = *(const uint4*)(px + 16), xd = *(const uint4*)(px + 24);
    float xo[32];
#define UNP8(V, O)                                                     \
    xo[(O) + 0] = bflo((V).x); xo[(O) + 1] = bfhi((V).x);              \
    xo[(O) + 2] = bflo((V).y); xo[(O) + 3] = bfhi((V).y);              \
    xo[(O) + 4] = bflo((V).z); xo[(O) + 5] = bfhi((V).z);              \
    xo[(O) + 6] = bflo((V).w); xo[(O) + 7] = bfhi((V).w);
    UNP8(xa, 0) UNP8(xb, 8) UNP8(xc, 16) UNP8(xd, 24)
#undef UNP8
#pragma unroll
    for (int q = 0; q < 32; ++q) q16[q] = f2bf(0.5f * acc[q] + 0.5f * xo[q]);
  } else {
#pragma unroll
    for (int q = 0; q < 32; ++q) q16[q] = 0;
  }
  {
    unsigned short* lrow = &lds[(tid >> 2) * LW + cq];
    *(uint4*)(lrow) = *(const uint4*)&q16[0];
    *(uint4*)(lrow + 8) = *(const uint4*)&q16[8];
    *(uint4*)(lrow + 16) = *(const uint4*)&q16[16];
    *(uint4*)(lrow + 24) = *(const uint4*)&q16[24];
  }
  __syncthreads();

  // phase 2: GEMM 64x128 (skip folded into W')
  const int lane = tid & 63;
  const int wid = tid >> 6;
  const int rq = (wid >> 1) * 32;
  const int colbase = (wid & 1) * 64;
  const int j = lane & 15, g = lane >> 4;

  bf16x8 bfrag[4][4];
#pragma unroll
  for (int c = 0; c < 4; ++c)
#pragma unroll
    for (int s = 0; s < 4; ++s)
      bfrag[c][s] =
          *(const bf16x8*)(Wt16 + (size_t)(colbase + 16 * c + j) * HID + 32 * s + 8 * g);

  const f32x4 zero = {0.f, 0.f, 0.f, 0.f};
#pragma unroll
  for (int rt = 0; rt < 2; ++rt) {
    bf16x8 af[4];
#pragma unroll
    for (int s = 0; s < 4; ++s)
      af[s] = *(const bf16x8*)&lds[(rq + rt * 16 + j) * LW + 32 * s + 8 * g];
    f32x4 a2[4] = {zero, zero, zero, zero};
#pragma unroll
    for (int s = 0; s < 4; ++s)
#pragma unroll
      for (int c = 0; c < 4; ++c)
        a2[c] = __builtin_amdgcn_mfma_f32_16x16x32_bf16(af[s], bfrag[c][s], a2[c], 0, 0, 0);
#pragma unroll
    for (int i = 0; i < 4; ++i) {
      const int rr = m0 + rq + rt * 16 + 4 * g + i;
      if (rr >= M) continue;
#pragma unroll
      for (int c = 0; c < 4; ++c) {
        const int col = colbase + 16 * c + j;
        float z = fmaxf(a2[c][i], 0.f);
        h8out[(size_t)rr * HID + col] = f2fp8(z);
        if (C16) C16[(size_t)rr * HID + col] = f2bf(z);
      }
    }
  }
}

// ---------------- fused lin2 + log_softmax via MFMA (permuted in, original out) ----------------
static __global__ __launch_bounds__(256, 3) void k_mlin2(
    const unsigned short* __restrict__ h16, const unsigned short* __restrict__ Wt2,
    const float* __restrict__ b2, const int* __restrict__ perm,
    float* __restrict__ out) {
  __shared__ unsigned short lds[128 * LW];
  const int tid = threadIdx.x;
  const int lane = tid & 63;
  const int wid = tid >> 6;
  const int j = lane & 15, g = lane >> 4;
  const int m0 = blockIdx.x * 128;

  bf16x8 bfrag[3][4];
#pragma unroll
  for (int c = 0; c < 3; ++c)
#pragma unroll
    for (int s = 0; s < 4; ++s)
      bfrag[c][s] = *(const bf16x8*)(Wt2 + (size_t)(16 * c + j) * HID + 32 * s + 8 * g);

  float bb[3];
#pragma unroll
  for (int c = 0; c < 3; ++c) {
    int col = 16 * c + j;
    bb[c] = (col < OUTC) ? b2[col] : -1e30f;
  }

#pragma unroll 2
  for (int i = 0; i < 8; ++i) {
    int idx = i * 256 + tid;
    int row = idx >> 4, ch = idx & 15;
    int grow = m0 + row;
    if (grow >= NN) grow = NN - 1;
    *(bf16x8*)&lds[row * LW + ch * 8] =
        *(const bf16x8*)(h16 + (size_t)grow * HID + ch * 8);
  }
  __syncthreads();

  const f32x4 zero = {0.f, 0.f, 0.f, 0.f};
#pragma unroll
  for (int rt = 0; rt < 2; ++rt) {
    bf16x8 af[4];
#pragma unroll
    for (int s = 0; s < 4; ++s)
      af[s] = *(const bf16x8*)&lds[(wid * 32 + rt * 16 + j) * LW + 32 * s + 8 * g];
    f32x4 acc[3] = {zero, zero, zero};
#pragma unroll
    for (int s = 0; s < 4; ++s)
#pragma unroll
      for (int c = 0; c < 3; ++c)
        acc[c] = __builtin_amdgcn_mfma_f32_16x16x32_bf16(af[s], bfrag[c][s], acc[c], 0, 0, 0);

#pragma unroll
    for (int i = 0; i < 4; ++i) {
      const int rr = m0 + wid * 32 + rt * 16 + 4 * g + i;
      if (rr >= NN) continue;
      float z0 = acc[0][i] + bb[0];
      float z1 = acc[1][i] + bb[1];
      float z2 = acc[2][i] + bb[2];
      float m = fmaxf(fmaxf(z0, z1), z2);
      m = fmaxf(m, __shfl_xor(m, 1));
      m = fmaxf(m, __shfl_xor(m, 2));
      m = fmaxf(m, __shfl_xor(m, 4));
      m = fmaxf(m, __shfl_xor(m, 8));
      float sum = __expf(z0 - m) + __expf(z1 - m) + __expf(z2 - m);
      sum += __shfl_xor(sum, 1);
      sum += __shfl_xor(sum, 2);
      sum += __shfl_xor(sum, 4);
      sum += __shfl_xor(sum, 8);
      float ls = m + logf(sum);
      int orig = perm[rr];
      out[(size_t)orig * OUTC + j] = z0 - ls;
      out[(size_t)orig * OUTC + 16 + j] = z1 - ls;
      if (j < 8) out[(size_t)orig * OUTC + 32 + j] = z2 - ls;
    }
  }
}

// ---------------- host ----------------
extern "C" void kernel_launch(void* const* d_in, const int* in_sizes, int n_in,
                              void* d_out, int out_size, void* d_ws, size_t ws_size,
                              hipStream_t stream) {
  const float* x  = (const float*)d_in[0];
  const int*   ei = (const int*)d_in[1];
  const float* w1 = (const float*)d_in[2];
  const float* b1 = (const float*)d_in[3];
  const float* cw = (const float*)d_in[4];
  const float* w2 = (const float*)d_in[5];
  const float* b2 = (const float*)d_in[6];
  float* out = (float*)d_out;

  char* ws = (char*)d_ws;
  size_t o = 0;
  auto carve = [&](size_t bytes) {
    void* p = ws + o;
    o = (o + bytes + 255) & ~(size_t)255;
    return p;
  };
  float* dinv   = (float*)carve((size_t)NN * 4);
  int*   offs   = (int*)carve((size_t)(NN + 1) * 4);
  int*   cursor = (int*)carve((size_t)NN * 4);
  int*   bcnt   = (int*)carve((size_t)NBUCK * 4);
  int*   boffs  = (int*)carve((size_t)(NBUCK + 1) * 4);
  int*   bcur   = (int*)carve((size_t)NBUCK * 4);
  int*   deg    = (int*)carve((size_t)NN * 4);
  int*   dbin   = (int*)carve(64 * 4);
  int*   dcur   = (int*)carve(64 * 4);
  int*   perm   = (int*)carve((size_t)NN * 4);
  int*   inv    = (int*)carve((size_t)NN * 4);
  int4*  hdr    = (int4*)carve((size_t)NN * 16);
  int2*  stage  = (int2*)carve((size_t)NE * 8);
  int2*  edata  = (int2*)carve((size_t)NE * 8);
  unsigned short* x016 = (unsigned short*)carve((size_t)NN * HID * 2);
  unsigned short* hb16 = (unsigned short*)carve((size_t)NN * HID * 2);
  unsigned char*  h8A  = (unsigned char*)carve((size_t)NN * HID);
  unsigned char*  h8B  = (unsigned char*)carve((size_t)NN * HID);
  unsigned short* wt1  = (unsigned short*)carve((size_t)INCH * HID * 2);
  unsigned short* wtl  = (unsigned short*)carve((size_t)NLAYERS * HID * HID * 2);
  unsigned short* wt2  = (unsigned short*)carve((size_t)48 * HID * 2);
  (void)ws_size; (void)in_sizes; (void)n_in; (void)out_size;

  const int TB = 256;
  const int gEB = (NE + EPB - 1) / EPB;  // 391

  k_zerob<<<(NBUCK + 255) / 256, TB, 0, stream>>>(bcnt, dbin);
  k_bhist<<<gEB, TB, 0, stream>>>(ei, bcnt);
  k_bscan<<<1, 512, 0, stream>>>(bcnt, boffs, bcur, offs);
  k_sortA<<<gEB, TB, 0, stream>>>(ei, bcur, stage);
  k_degs<<<NBUCK, TB, 0, stream>>>(stage, boffs, offs, dinv, cursor, deg, dbin);
  k_dscan<<<1, 64, 0, stream>>>(dbin, dcur);
  k_perm<<<NBUCK, TB, 0, stream>>>(deg, dcur, perm, inv);
  k_hdr<<<NBUCK, TB, 0, stream>>>(perm, offs, dinv, hdr);
  k_passB2<<<NBUCK, TB, 0, stream>>>(stage, boffs, offs, dinv, inv, cursor, edata);

  const int cvtTotal = INCH * HID + NLAYERS * HID * HID + 48 * HID;
  k_cvtall<<<(cvtTotal + 255) / 256, 256, 0, stream>>>(w1, cw, w2, wt1, wtl, wt2);

  k_lin1<<<(NN + 31) / 32, 256, 0, stream>>>(x, wt1, b1, inv, x016, h8A, NN);

  const int gF = (NN + 63) / 64;  // 1563
  const unsigned char* hin = h8A;
  unsigned char* hout = h8B;
  for (int l = 0; l < NLAYERS; ++l) {
    unsigned short* c16 = (l == NLAYERS - 1) ? hb16 : nullptr;
    k_fused<<<gF, 256, 0, stream>>>(hin, x016, hdr, edata,
                                    wtl + (size_t)l * HID * HID, hout, c16, NN);
    hin = hout;
    hout = (hout == h8A) ? h8B : h8A;
  }
  k_mlin2<<<(NN + 127) / 128, 256, 0, stream>>>(hb16, wt2, b2, perm, out);
}

// Round 20
// 558.059 us; speedup vs baseline: 1.0163x; 1.0163x over previous
//
#include <hip/hip_runtime.h>
#include <math.h>

#define NN 100000
#define NE 1600000
#define HID 128
#define INCH 256
#define OUTC 40
#define NLAYERS 8
#define NBUCK 391   // ceil(NN/256)
#define EPB 4096
#define CAP 6144
#define LW 136      // LDS row stride in ushorts (272 B)

typedef __attribute__((ext_vector_type(8))) short bf16x8;
typedef __attribute__((ext_vector_type(4))) float f32x4;
typedef __attribute__((ext_vector_type(2))) float f32x2;

static __device__ inline unsigned short f2bf(float f) {
  unsigned u = __float_as_uint(f);
  unsigned r = (u + 0x7fff + ((u >> 16) & 1)) >> 16;
  return (unsigned short)r;
}
static __device__ inline float bflo(unsigned u) { return __uint_as_float(u << 16); }
static __device__ inline float bfhi(unsigned u) { return __uint_as_float(u & 0xffff0000u); }
static __device__ inline unsigned char f2fp8(float f) {
  return (unsigned char)(__builtin_amdgcn_cvt_pk_fp8_f32(f, f, 0, false) & 0xff);
}

// ---------------- preprocessing (atomic-light counting sort + degree perm) ----------------

static __global__ void k_zerob(int* __restrict__ bcnt, int* __restrict__ dbin) {
  int i = blockIdx.x * 256 + threadIdx.x;
  if (i < NBUCK) bcnt[i] = 0;
  if (i < 64) dbin[i] = 0;
}

static __global__ __launch_bounds__(256) void k_bhist(const int* __restrict__ ei,
                                                      int* __restrict__ bcnt) {
  __shared__ int lh[NBUCK + 1];
  int t = threadIdx.x;
  for (int i = t; i <= NBUCK; i += 256) lh[i] = 0;
  __syncthreads();
  int e0 = blockIdx.x * EPB;
  for (int k = t; k < EPB; k += 256) {
    int e = e0 + k;
    if (e < NE) atomicAdd(&lh[ei[NE + e] >> 8], 1);
  }
  __syncthreads();
  for (int i = t; i < NBUCK; i += 256)
    if (lh[i]) atomicAdd(&bcnt[i], lh[i]);
}

static __global__ void k_bscan(const int* __restrict__ bcnt, int* __restrict__ boffs,
                               int* __restrict__ bcur, int* __restrict__ offs) {
  __shared__ int sd[512];
  int t = threadIdx.x;
  sd[t] = (t < NBUCK) ? bcnt[t] : 0;
  __syncthreads();
  for (int d = 1; d < 512; d <<= 1) {
    int v = (t >= d) ? sd[t - d] : 0;
    __syncthreads();
    sd[t] += v;
    __syncthreads();
  }
  if (t < NBUCK) {
    boffs[t + 1] = sd[t];
    bcur[t] = sd[t] - bcnt[t];
  }
  if (t == 0) { boffs[0] = 0; offs[NN] = NE; }
}

static __global__ __launch_bounds__(256) void k_sortA(const int* __restrict__ ei,
                                                      int* __restrict__ bcur,
                                                      int2* __restrict__ stage) {
  __shared__ int lsrc[EPB], ldst[EPB];
  __shared__ int lh[NBUCK + 1], lbase[NBUCK + 1], lcur[NBUCK + 1];
  int t = threadIdx.x;
  int e0 = blockIdx.x * EPB;
  for (int k = t; k < EPB; k += 256) {
    int e = e0 + k;
    lsrc[k] = (e < NE) ? ei[e] : -1;
    ldst[k] = (e < NE) ? ei[NE + e] : -1;
  }
  for (int i = t; i <= NBUCK; i += 256) lh[i] = 0;
  __syncthreads();
  for (int k = t; k < EPB; k += 256)
    if (ldst[k] >= 0) atomicAdd(&lh[ldst[k] >> 8], 1);
  __syncthreads();
  for (int i = t; i < NBUCK; i += 256) {
    int c = lh[i];
    lbase[i] = c ? atomicAdd(&bcur[i], c) : 0;
    lcur[i] = 0;
  }
  __syncthreads();
  for (int k = t; k < EPB; k += 256) {
    int d = ldst[k];
    if (d >= 0) {
      int bu = d >> 8;
      int r = atomicAdd(&lcur[bu], 1);
      stage[lbase[bu] + r] = make_int2(lsrc[k], d);
    }
  }
}

static __global__ __launch_bounds__(256) void k_degs(
    const int2* __restrict__ stage, const int* __restrict__ boffs,
    int* __restrict__ offs, float* __restrict__ dinv, int* __restrict__ cursor,
    int* __restrict__ deg, int* __restrict__ dbin) {
  __shared__ int lcnt[256];
  __shared__ int sd[256];
  __shared__ int lhd[64];
  int b = blockIdx.x, t = threadIdx.x;
  int sb = boffs[b], se = boffs[b + 1];
  int cntb = se - sb;
  int nb0 = b << 8;
  lcnt[t] = 0;
  if (t < 64) lhd[t] = 0;
  __syncthreads();
  for (int k = t; k < cntb; k += 256) atomicAdd(&lcnt[stage[sb + k].y - nb0], 1);
  __syncthreads();
  int v = lcnt[t];
  sd[t] = v;
  __syncthreads();
  for (int d = 1; d < 256; d <<= 1) {
    int u = (t >= d) ? sd[t - d] : 0;
    __syncthreads();
    sd[t] += u;
    __syncthreads();
  }
  int n = nb0 + t;
  if (n < NN) {
    int o = sb + sd[t] - v;
    offs[n] = o;
    cursor[n] = o;
    dinv[n] = rsqrtf((float)(v + 1));
    deg[n] = v;
    int bin = 63 - (v > 63 ? 63 : v);  // heavy nodes first
    atomicAdd(&lhd[bin], 1);
  }
  __syncthreads();
  if (t < 64 && lhd[t]) atomicAdd(&dbin[t], lhd[t]);
}

static __global__ void k_dscan(const int* __restrict__ dbin, int* __restrict__ dcur) {
  __shared__ int sd[64];
  int t = threadIdx.x;
  sd[t] = dbin[t];
  __syncthreads();
  if (t == 0) {
    int a = 0;
    for (int i = 0; i < 64; ++i) { int v = sd[i]; sd[i] = a; a += v; }
  }
  __syncthreads();
  dcur[t] = sd[t];
}

static __global__ __launch_bounds__(256) void k_perm(const int* __restrict__ deg,
                                                     int* __restrict__ dcur,
                                                     int* __restrict__ perm,
                                                     int* __restrict__ inv) {
  __shared__ int lh[64], lbase[64], lcur[64];
  int t = threadIdx.x;
  int n = blockIdx.x * 256 + t;
  if (t < 64) { lh[t] = 0; lcur[t] = 0; }
  __syncthreads();
  int bin = 0;
  if (n < NN) {
    int d = deg[n];
    bin = 63 - (d > 63 ? 63 : d);
    atomicAdd(&lh[bin], 1);
  }
  __syncthreads();
  if (t < 64) lbase[t] = lh[t] ? atomicAdd(&dcur[t], lh[t]) : 0;
  __syncthreads();
  if (n < NN) {
    int r = atomicAdd(&lcur[bin], 1);
    int pos = lbase[bin] + r;
    perm[pos] = n;
    inv[n] = pos;
  }
}

// node header for fused: {offs_begin, offs_end, dinv^2, 0} in permuted order
static __global__ void k_hdr(const int* __restrict__ perm, const int* __restrict__ offs,
                             const float* __restrict__ dinv, int4* __restrict__ hdr) {
  int i = blockIdx.x * 256 + threadIdx.x;
  if (i < NN) {
    int n = perm[i];
    float d = dinv[n];
    hdr[i] = make_int4(offs[n], offs[n + 1], __float_as_int(d * d), 0);
  }
}

// edata.x = inv[src] (permuted-space source index)
static __global__ __launch_bounds__(256) void k_passB2(
    const int2* __restrict__ stage, const int* __restrict__ boffs,
    const int* __restrict__ offs, const float* __restrict__ dinv,
    const int* __restrict__ inv, int* __restrict__ cursor, int2* __restrict__ edata) {
  __shared__ int2 lbuf[CAP];
  __shared__ int lcur[256];
  int b = blockIdx.x, t = threadIdx.x;
  int sb = boffs[b], se = boffs[b + 1];
  int cntb = se - sb;
  int nb0 = b << 8;
  if (cntb <= CAP) {
    if (nb0 + t < NN) lcur[t] = offs[nb0 + t] - sb;
    __syncthreads();
    for (int k = t; k < cntb; k += 256) {
      int2 sd_ = stage[sb + k];
      float w = dinv[sd_.x] * dinv[sd_.y];
      int p = atomicAdd(&lcur[sd_.y - nb0], 1);
      lbuf[p] = make_int2(inv[sd_.x], __float_as_int(w));
    }
    __syncthreads();
    for (int k = t; k < cntb; k += 256) edata[sb + k] = lbuf[k];
  } else {
    for (int k = t; k < cntb; k += 256) {
      int2 sd_ = stage[sb + k];
      float w = dinv[sd_.x] * dinv[sd_.y];
      int p = atomicAdd(&cursor[sd_.y], 1);
      edata[p] = make_int2(inv[sd_.x], __float_as_int(w));
    }
  }
}

// ---------------- merged weight conversion ----------------
static __global__ void k_cvtall(const float* __restrict__ W1, const float* __restrict__ CW,
                                const float* __restrict__ W2, unsigned short* __restrict__ wt1,
                                unsigned short* __restrict__ wtl,
                                unsigned short* __restrict__ wt2) {
  int idx = blockIdx.x * 256 + threadIdx.x;
  if (idx < INCH * HID) {
    int k = idx >> 7, n = idx & 127;
    wt1[(size_t)n * INCH + k] = f2bf(W1[idx]);
  } else if (idx < INCH * HID + NLAYERS * HID * HID) {
    int r = idx - INCH * HID;
    int l = r >> 14, rem = r & 16383;
    int k = rem >> 7, n = rem & 127;
    float beta = logf(1.0f / (float)(l + 1) + 1.0f);
    float v = beta * CW[r];
    if (k == n) v += 1.0f - beta;
    wtl[(size_t)l * HID * HID + n * HID + k] = f2bf(v);
  } else if (idx < INCH * HID + NLAYERS * HID * HID + 48 * HID) {
    int r = idx - INCH * HID - NLAYERS * HID * HID;
    int n = r >> 7, k = r & 127;
    wt2[r] = (n < OUTC) ? f2bf(W2[(size_t)k * OUTC + n]) : 0;
  }
}

// ---------------- lin1: 64-row tiles, streaming reads, scattered row writes ----------
__global__ __launch_bounds__(256, 4) void k_lin1(
    const float* __restrict__ A32, const unsigned short* __restrict__ Wt16,
    const float* __restrict__ bias, const int* __restrict__ inv,
    unsigned short* __restrict__ C16, unsigned char* __restrict__ C8, int M) {
  __shared__ unsigned short lds[64 * LW];
  __shared__ int ldst[64];
  const int tid = threadIdx.x;
  const int lane = tid & 63;
  const int wid = tid >> 6;
  const int j = lane & 15, g = lane >> 4;
  const int rq = (wid >> 1) * 32;
  const int colbase = (wid & 1) * 64;
  const int m0 = blockIdx.x * 64;

  if (tid < 64) {
    int r = m0 + tid;
    ldst[tid] = inv[r >= M ? M - 1 : r];
  }

  f32x4 acc[2][4];
  const f32x4 zero = {0.f, 0.f, 0.f, 0.f};
#pragma unroll
  for (int rt = 0; rt < 2; ++rt)
#pragma unroll
    for (int c = 0; c < 4; ++c) acc[rt][c] = zero;

#pragma unroll 1
  for (int kc = 0; kc < 2; ++kc) {
    __syncthreads();
#pragma unroll
    for (int u = 0; u < 4; ++u) {
      int idx = u * 256 + tid;
      int row = idx >> 4, ch = idx & 15;
      int grow = m0 + row;
      if (grow >= M) grow = M - 1;
      const float* p = A32 + (size_t)grow * INCH + kc * 128 + ch * 8;
      float4 u0 = *(const float4*)p;
      float4 u1 = *(const float4*)(p + 4);
      bf16x8 v;
      v[0] = (short)f2bf(u0.x); v[1] = (short)f2bf(u0.y);
      v[2] = (short)f2bf(u0.z); v[3] = (short)f2bf(u0.w);
      v[4] = (short)f2bf(u1.x); v[5] = (short)f2bf(u1.y);
      v[6] = (short)f2bf(u1.z); v[7] = (short)f2bf(u1.w);
      *(bf16x8*)&lds[row * LW + ch * 8] = v;
    }
    __syncthreads();
    bf16x8 bfrag[4][4];
#pragma unroll
    for (int c = 0; c < 4; ++c)
#pragma unroll
      for (int s = 0; s < 4; ++s)
        bfrag[c][s] = *(const bf16x8*)(Wt16 + (size_t)(colbase + 16 * c + j) * INCH +
                                       kc * 128 + 32 * s + 8 * g);
#pragma unroll
    for (int rt = 0; rt < 2; ++rt) {
      bf16x8 af[4];
#pragma unroll
      for (int s = 0; s < 4; ++s)
        af[s] = *(const bf16x8*)&lds[(rq + rt * 16 + j) * LW + 32 * s + 8 * g];
#pragma unroll
      for (int s = 0; s < 4; ++s)
#pragma unroll
        for (int c = 0; c < 4; ++c)
          acc[rt][c] =
              __builtin_amdgcn_mfma_f32_16x16x32_bf16(af[s], bfrag[c][s], acc[rt][c], 0, 0, 0);
    }
  }

  // stage result tile (bf16) into LDS
  __syncthreads();
#pragma unroll
  for (int rt = 0; rt < 2; ++rt)
#pragma unroll
    for (int i = 0; i < 4; ++i) {
      const int row = rq + rt * 16 + 4 * g + i;
#pragma unroll
      for (int c = 0; c < 4; ++c) {
        const int col = colbase + 16 * c + j;
        lds[row * LW + col] = f2bf(fmaxf(acc[rt][c][i] + bias[col], 0.f));
      }
    }
  __syncthreads();

  // scattered row-chunk writes: thread -> (row = tid>>2, 32-short chunk = tid&3)
  {
    const int r = tid >> 2, q = tid & 3;
    if (m0 + r < M) {
      const unsigned short* src = &lds[r * LW + q * 32];
      uint4 v0 = *(const uint4*)(src);
      uint4 v1 = *(const uint4*)(src + 8);
      uint4 v2 = *(const uint4*)(src + 16);
      uint4 v3 = *(const uint4*)(src + 24);
      size_t base = (size_t)ldst[r] * HID + q * 32;
      *(uint4*)(C16 + base) = v0;
      *(uint4*)(C16 + base + 8) = v1;
      *(uint4*)(C16 + base + 16) = v2;
      *(uint4*)(C16 + base + 24) = v3;
      unsigned char q8[32];
      const unsigned* uu0 = (const unsigned*)&v0;
      const unsigned* uu1 = (const unsigned*)&v1;
      const unsigned* uu2 = (const unsigned*)&v2;
      const unsigned* uu3 = (const unsigned*)&v3;
#pragma unroll
      for (int s = 0; s < 4; ++s) {
        q8[2 * s] = f2fp8(bflo(uu0[s]));       q8[2 * s + 1] = f2fp8(bfhi(uu0[s]));
        q8[8 + 2 * s] = f2fp8(bflo(uu1[s]));   q8[9 + 2 * s] = f2fp8(bfhi(uu1[s]));
        q8[16 + 2 * s] = f2fp8(bflo(uu2[s]));  q8[17 + 2 * s] = f2fp8(bfhi(uu2[s]));
        q8[24 + 2 * s] = f2fp8(bflo(uu3[s]));  q8[25 + 2 * s] = f2fp8(bfhi(uu3[s]));
      }
      *(uint4*)(C8 + base) = *(const uint4*)&q8[0];
      *(uint4*)(C8 + base + 16) = *(const uint4*)&q8[16];
    }
  }
}

// ---------------- fused layer: agg (fp8 gather, 2-deep pipeline, hdr) + GEMM ----------------
#define ACCD(U, O, W)                                                   \
  {                                                                     \
    f32x2 lo_ = __builtin_amdgcn_cvt_pk_f32_fp8((U), false);            \
    f32x2 hi_ = __builtin_amdgcn_cvt_pk_f32_fp8((U), true);             \
    acc[(O) + 0] = fmaf((W), lo_.x, acc[(O) + 0]);                      \
    acc[(O) + 1] = fmaf((W), lo_.y, acc[(O) + 1]);                      \
    acc[(O) + 2] = fmaf((W), hi_.x, acc[(O) + 2]);                      \
    acc[(O) + 3] = fmaf((W), hi_.y, acc[(O) + 3]);                      \
  }

#define ACCROW8(VA, VB, W)                                              \
  ACCD((VA).x, 0, W) ACCD((VA).y, 4, W) ACCD((VA).z, 8, W) ACCD((VA).w, 12, W) \
  ACCD((VB).x, 16, W) ACCD((VB).y, 20, W) ACCD((VB).z, 24, W) ACCD((VB).w, 28, W)

__global__ __launch_bounds__(256) void k_fused(
    const unsigned char* __restrict__ h8, const unsigned short* __restrict__ x016,
    const int4* __restrict__ hdr, const int2* __restrict__ edata,
    const unsigned short* __restrict__ Wt16, unsigned char* __restrict__ h8out,
    unsigned short* __restrict__ C16, int M) {
  __shared__ unsigned short lds[64 * LW];
  const int tid = threadIdx.x;
  const int m0 = blockIdx.x * 64;
  const int newid = m0 + (tid >> 2);
  const int cq = (tid & 3) * 32;

  float acc[32];
#pragma unroll
  for (int q = 0; q < 32; ++q) acc[q] = 0.f;

  unsigned short q16[32];
  if (newid < M) {
    const int4 hd = hdr[newid];
    const int b = hd.x, e = hd.y;
    {  // self loop
      const unsigned char* p = h8 + (size_t)newid * HID + cq;
      uint4 s0 = *(const uint4*)p, s1 = *(const uint4*)(p + 16);
      float w = __int_as_float(hd.z);
      ACCROW8(s0, s1, w)
    }
    int i = b;
    int2 n0, n1;
    if (i + 3 < e) { n0 = edata[i]; n1 = edata[i + 1]; }
    for (; i + 3 < e; i += 2) {
      int2 c0 = n0, c1 = n1;
      n0 = edata[i + 2];
      n1 = edata[i + 3];
      const unsigned char* p0 = h8 + (size_t)c0.x * HID + cq;
      const unsigned char* p1 = h8 + (size_t)c1.x * HID + cq;
      uint4 r0 = *(const uint4*)p0, r1 = *(const uint4*)(p0 + 16);
      uint4 r2 = *(const uint4*)p1, r3 = *(const uint4*)(p1 + 16);
      float w0 = __int_as_float(c0.y), w1 = __int_as_float(c1.y);
      ACCROW8(r0, r1, w0)
      ACCROW8(r2, r3, w1)
    }
    for (; i < e; ++i) {
      int2 e0 = edata[i];
      const unsigned char* p0 = h8 + (size_t)e0.x * HID + cq;
      uint4 r0 = *(const uint4*)p0, r1 = *(const uint4*)(p0 + 16);
      float w0 = __int_as_float(e0.y);
      ACCROW8(r0, r1, w0)
    }
    const unsigned short* px = x016 + (size_t)newid * HID + cq;
    uint4 xa = *(const uint4*)px, xb = *(const uint4*)(px + 8);
    uint4 xc = *(const uint4*)(px + 16), xd = *(const uint4*)(px + 24);
    float xo[32];
#define UNP8(V, O)                                                     \
    xo[(O) + 0] = bflo((V).x); xo[(O) + 1] = bfhi((V).x);              \
    xo[(O) + 2] = bflo((V).y); xo[(O) + 3] = bfhi((V).y);              \
    xo[(O) + 4] = bflo((V).z); xo[(O) + 5] = bfhi((V).z);              \
    xo[(O) + 6] = bflo((V).w); xo[(O) + 7] = bfhi((V).w);
    UNP8(xa, 0) UNP8(xb, 8) UNP8(xc, 16) UNP8(xd, 24)
#undef UNP8
#pragma unroll
    for (int q = 0; q < 32; ++q) q16[q] = f2bf(0.5f * acc[q] + 0.5f * xo[q]);
  } else {
#pragma unroll
    for (int q = 0; q < 32; ++q) q16[q] = 0;
  }
  {
    unsigned short* lrow = &lds[(tid >> 2) * LW + cq];
    *(uint4*)(lrow) = *(const uint4*)&q16[0];
    *(uint4*)(lrow + 8) = *(const uint4*)&q16[8];
    *(uint4*)(lrow + 16) = *(const uint4*)&q16[16];
    *(uint4*)(lrow + 24) = *(const uint4*)&q16[24];
  }
  __syncthreads();

  // phase 2: GEMM 64x128 (skip folded into W')
  const int lane = tid & 63;
  const int wid = tid >> 6;
  const int rq = (wid >> 1) * 32;
  const int colbase = (wid & 1) * 64;
  const int j = lane & 15, g = lane >> 4;

  bf16x8 bfrag[4][4];
#pragma unroll
  for (int c = 0; c < 4; ++c)
#pragma unroll
    for (int s = 0; s < 4; ++s)
      bfrag[c][s] =
          *(const bf16x8*)(Wt16 + (size_t)(colbase + 16 * c + j) * HID + 32 * s + 8 * g);

  const f32x4 zero = {0.f, 0.f, 0.f, 0.f};
#pragma unroll
  for (int rt = 0; rt < 2; ++rt) {
    bf16x8 af[4];
#pragma unroll
    for (int s = 0; s < 4; ++s)
      af[s] = *(const bf16x8*)&lds[(rq + rt * 16 + j) * LW + 32 * s + 8 * g];
    f32x4 a2[4] = {zero, zero, zero, zero};
#pragma unroll
    for (int s = 0; s < 4; ++s)
#pragma unroll
      for (int c = 0; c < 4; ++c)
        a2[c] = __builtin_amdgcn_mfma_f32_16x16x32_bf16(af[s], bfrag[c][s], a2[c], 0, 0, 0);
#pragma unroll
    for (int i = 0; i < 4; ++i) {
      const int rr = m0 + rq + rt * 16 + 4 * g + i;
      if (rr >= M) continue;
#pragma unroll
      for (int c = 0; c < 4; ++c) {
        const int col = colbase + 16 * c + j;
        float z = fmaxf(a2[c][i], 0.f);
        h8out[(size_t)rr * HID + col] = f2fp8(z);
        if (C16) C16[(size_t)rr * HID + col] = f2bf(z);
      }
    }
  }
}

// ---------------- fused lin2 + log_softmax via MFMA (permuted in, original out) ----------------
static __global__ __launch_bounds__(256, 3) void k_mlin2(
    const unsigned short* __restrict__ h16, const unsigned short* __restrict__ Wt2,
    const float* __restrict__ b2, const int* __restrict__ perm,
    float* __restrict__ out) {
  __shared__ unsigned short lds[128 * LW];
  const int tid = threadIdx.x;
  const int lane = tid & 63;
  const int wid = tid >> 6;
  const int j = lane & 15, g = lane >> 4;
  const int m0 = blockIdx.x * 128;

  bf16x8 bfrag[3][4];
#pragma unroll
  for (int c = 0; c < 3; ++c)
#pragma unroll
    for (int s = 0; s < 4; ++s)
      bfrag[c][s] = *(const bf16x8*)(Wt2 + (size_t)(16 * c + j) * HID + 32 * s + 8 * g);

  float bb[3];
#pragma unroll
  for (int c = 0; c < 3; ++c) {
    int col = 16 * c + j;
    bb[c] = (col < OUTC) ? b2[col] : -1e30f;
  }

#pragma unroll 2
  for (int i = 0; i < 8; ++i) {
    int idx = i * 256 + tid;
    int row = idx >> 4, ch = idx & 15;
    int grow = m0 + row;
    if (grow >= NN) grow = NN - 1;
    *(bf16x8*)&lds[row * LW + ch * 8] =
        *(const bf16x8*)(h16 + (size_t)grow * HID + ch * 8);
  }
  __syncthreads();

  const f32x4 zero = {0.f, 0.f, 0.f, 0.f};
#pragma unroll
  for (int rt = 0; rt < 2; ++rt) {
    bf16x8 af[4];
#pragma unroll
    for (int s = 0; s < 4; ++s)
      af[s] = *(const bf16x8*)&lds[(wid * 32 + rt * 16 + j) * LW + 32 * s + 8 * g];
    f32x4 acc[3] = {zero, zero, zero};
#pragma unroll
    for (int s = 0; s < 4; ++s)
#pragma unroll
      for (int c = 0; c < 3; ++c)
        acc[c] = __builtin_amdgcn_mfma_f32_16x16x32_bf16(af[s], bfrag[c][s], acc[c], 0, 0, 0);

#pragma unroll
    for (int i = 0; i < 4; ++i) {
      const int rr = m0 + wid * 32 + rt * 16 + 4 * g + i;
      if (rr >= NN) continue;
      float z0 = acc[0][i] + bb[0];
      float z1 = acc[1][i] + bb[1];
      float z2 = acc[2][i] + bb[2];
      float m = fmaxf(fmaxf(z0, z1), z2);
      m = fmaxf(m, __shfl_xor(m, 1));
      m = fmaxf(m, __shfl_xor(m, 2));
      m = fmaxf(m, __shfl_xor(m, 4));
      m = fmaxf(m, __shfl_xor(m, 8));
      float sum = __expf(z0 - m) + __expf(z1 - m) + __expf(z2 - m);
      sum += __shfl_xor(sum, 1);
      sum += __shfl_xor(sum, 2);
      sum += __shfl_xor(sum, 4);
      sum += __shfl_xor(sum, 8);
      float ls = m + logf(sum);
      int orig = perm[rr];
      out[(size_t)orig * OUTC + j] = z0 - ls;
      out[(size_t)orig * OUTC + 16 + j] = z1 - ls;
      if (j < 8) out[(size_t)orig * OUTC + 32 + j] = z2 - ls;
    }
  }
}

// ---------------- host ----------------
extern "C" void kernel_launch(void* const* d_in, const int* in_sizes, int n_in,
                              void* d_out, int out_size, void* d_ws, size_t ws_size,
                              hipStream_t stream) {
  const float* x  = (const float*)d_in[0];
  const int*   ei = (const int*)d_in[1];
  const float* w1 = (const float*)d_in[2];
  const float* b1 = (const float*)d_in[3];
  const float* cw = (const float*)d_in[4];
  const float* w2 = (const float*)d_in[5];
  const float* b2 = (const float*)d_in[6];
  float* out = (float*)d_out;

  char* ws = (char*)d_ws;
  size_t o = 0;
  auto carve = [&](size_t bytes) {
    void* p = ws + o;
    o = (o + bytes + 255) & ~(size_t)255;
    return p;
  };
  float* dinv   = (float*)carve((size_t)NN * 4);
  int*   offs   = (int*)carve((size_t)(NN + 1) * 4);
  int*   cursor = (int*)carve((size_t)NN * 4);
  int*   bcnt   = (int*)carve((size_t)NBUCK * 4);
  int*   boffs  = (int*)carve((size_t)(NBUCK + 1) * 4);
  int*   bcur   = (int*)carve((size_t)NBUCK * 4);
  int*   deg    = (int*)carve((size_t)NN * 4);
  int*   dbin   = (int*)carve(64 * 4);
  int*   dcur   = (int*)carve(64 * 4);
  int*   perm   = (int*)carve((size_t)NN * 4);
  int*   inv    = (int*)carve((size_t)NN * 4);
  int4*  hdr    = (int4*)carve((size_t)NN * 16);
  int2*  stage  = (int2*)carve((size_t)NE * 8);
  int2*  edata  = (int2*)carve((size_t)NE * 8);
  unsigned short* x016 = (unsigned short*)carve((size_t)NN * HID * 2);
  unsigned short* hb16 = (unsigned short*)carve((size_t)NN * HID * 2);
  unsigned char*  h8A  = (unsigned char*)carve((size_t)NN * HID);
  unsigned char*  h8B  = (unsigned char*)carve((size_t)NN * HID);
  unsigned short* wt1  = (unsigned short*)carve((size_t)INCH * HID * 2);
  unsigned short* wtl  = (unsigned short*)carve((size_t)NLAYERS * HID * HID * 2);
  unsigned short* wt2  = (unsigned short*)carve((size_t)48 * HID * 2);
  (void)ws_size; (void)in_sizes; (void)n_in; (void)out_size;

  const int TB = 256;
  const int gEB = (NE + EPB - 1) / EPB;  // 391

  k_zerob<<<(NBUCK + 255) / 256, TB, 0, stream>>>(bcnt, dbin);
  k_bhist<<<gEB, TB, 0, stream>>>(ei, bcnt);
  k_bscan<<<1, 512, 0, stream>>>(bcnt, boffs, bcur, offs);
  k_sortA<<<gEB, TB, 0, stream>>>(ei, bcur, stage);
  k_degs<<<NBUCK, TB, 0, stream>>>(stage, boffs, offs, dinv, cursor, deg, dbin);
  k_dscan<<<1, 64, 0, stream>>>(dbin, dcur);
  k_perm<<<NBUCK, TB, 0, stream>>>(deg, dcur, perm, inv);
  k_hdr<<<NBUCK, TB, 0, stream>>>(perm, offs, dinv, hdr);
  k_passB2<<<NBUCK, TB, 0, stream>>>(stage, boffs, offs, dinv, inv, cursor, edata);

  const int cvtTotal = INCH * HID + NLAYERS * HID * HID + 48 * HID;
  k_cvtall<<<(cvtTotal + 255) / 256, 256, 0, stream>>>(w1, cw, w2, wt1, wtl, wt2);

  const int gF = (NN + 63) / 64;  // 1563
  k_lin1<<<gF, 256, 0, stream>>>(x, wt1, b1, inv, x016, h8A, NN);

  const unsigned char* hin = h8A;
  unsigned char* hout = h8B;
  for (int l = 0; l < NLAYERS; ++l) {
    unsigned short* c16 = (l == NLAYERS - 1) ? hb16 : nullptr;
    k_fused<<<gF, 256, 0, stream>>>(hin, x016, hdr, edata,
                                    wtl + (size_t)l * HID * HID, hout, c16, NN);
    hin = hout;
    hout = (hout == h8A) ? h8B : h8A;
  }
  k_mlin2<<<(NN + 127) / 128, 256, 0, stream>>>(hb16, wt2, b2, perm, out);
}